// Round 14
// baseline (362.998 us; speedup 1.0000x reference)
//
#include <hip/hip_runtime.h>
#include <hip/hip_bf16.h>

#define NRELS 8
#define NB 8
#define PBLK 256          // partition blocks
#define BSH 9             // dsts per bucket = 512
#define BCAP 3584         // max edges per bucket staged in LDS

typedef __attribute__((ext_vector_type(8))) short short8v;
typedef __attribute__((ext_vector_type(4))) float f32x4;

__device__ __forceinline__ short bfc(float f) {
    __hip_bfloat16 h = __float2bfloat16(f);
    return *reinterpret_cast<short*>(&h);
}
__device__ __forceinline__ float bf2f(ushort u) {
    return __uint_as_float((unsigned)u << 16);
}

// ---- W in fused-K MFMA B-frag order. K = 512 = (rel, k64); frag (ks, nt):
// lane holds W[k512 = ks*32 + (lane>>4)*8 + j][c = nt*16 + (lane&15)], r = k512>>6.
// Wf1: 16 ks x 4 nt (OUT=64) = 64KB. Wf2: 16 ks x 2 nt (OUT=32) = 32KB.
__global__ void wprep_kernel(const float* __restrict__ basis1, const float* __restrict__ comp1,
                             const float* __restrict__ basis2, const float* __restrict__ comp2,
                             short* __restrict__ Wf1, short* __restrict__ Wf2) {
    int idx = blockIdx.x * blockDim.x + threadIdx.x;
    const int n1 = 16 * 4 * 64 * 8;   // 32768
    const int n2 = 16 * 2 * 64 * 8;   // 16384
    if (idx < n1) {
        int j = idx & 7, lane = (idx >> 3) & 63, nt = (idx >> 9) & 3, ks = idx >> 11;
        int k512 = ks * 32 + (lane >> 4) * 8 + j;
        int r = k512 >> 6, k64 = k512 & 63;
        int c = nt * 16 + (lane & 15);
        float s = 0.f;
#pragma unroll
        for (int b = 0; b < NB; ++b)
            s = fmaf(comp1[r * NB + b], basis1[b * 4096 + k64 * 64 + c], s);
        Wf1[idx] = bfc(s);
    } else if (idx < n1 + n2) {
        int i2 = idx - n1;
        int j = i2 & 7, lane = (i2 >> 3) & 63, nt = (i2 >> 9) & 1, ks = i2 >> 10;
        int k512 = ks * 32 + (lane >> 4) * 8 + j;
        int r = k512 >> 6, k64 = k512 & 63;
        int c = nt * 16 + (lane & 15);
        float s = 0.f;
#pragma unroll
        for (int b = 0; b < NB; ++b)
            s = fmaf(comp2[r * NB + b], basis2[b * 2048 + k64 * 32 + c], s);
        Wf2[i2] = bfc(s);
    }
}

// fp32 -> bf16 (vector x4)
__global__ void cvt_kernel(const float* __restrict__ in, ushort* __restrict__ outb, int n4) {
    for (int i = blockIdx.x * blockDim.x + threadIdx.x; i < n4;
         i += gridDim.x * blockDim.x) {
        float4 v = reinterpret_cast<const float4*>(in)[i];
        ushort4 o;
        o.x = (ushort)bfc(v.x); o.y = (ushort)bfc(v.y);
        o.z = (ushort)bfc(v.z); o.w = (ushort)bfc(v.w);
        reinterpret_cast<ushort4*>(outb)[i] = o;
    }
}

// ---- sort stage 1: per-block coarse histogram; histM layout [bucket][block] ----
__global__ void histA_kernel(const int* __restrict__ dst, int* __restrict__ histM,
                             int nEdges, int nBuck, int chunk) {
    __shared__ int h[512];
    for (int t = threadIdx.x; t < nBuck; t += 256) h[t] = 0;
    __syncthreads();
    int start = blockIdx.x * chunk;
    int end = min(nEdges, start + chunk);
    for (int i = start + threadIdx.x; i < end; i += 256)
        atomicAdd(&h[dst[i] >> BSH], 1);
    __syncthreads();
    for (int t = threadIdx.x; t < nBuck; t += 256)
        histM[t * PBLK + blockIdx.x] = h[t];
}

// ---- sort stage 2 (R12-verified): totals scan -> bucketBase + per-(bucket,block) offs ----
__global__ void scanA_kernel(const int* __restrict__ histM, int* __restrict__ offs,
                             int* __restrict__ bucketBase, int nBuck, int nBlk, int nEdges) {
    __shared__ int tot[512];
    const int b = threadIdx.x;
    int s = 0;
    if (b < nBuck) {
        const int4* hp = (const int4*)(histM + b * nBlk);
        for (int k = 0; k < nBlk / 4; ++k) {
            int4 v = hp[k];
            s += v.x + v.y + v.z + v.w;
        }
    }
    tot[b] = s;
    __syncthreads();
    int own = s;
    for (int st = 1; st < 512; st <<= 1) {
        int t = (b >= st) ? tot[b - st] : 0;
        __syncthreads();
        tot[b] += t;
        __syncthreads();
    }
    int base = tot[b] - own;   // exclusive
    if (b < nBuck) {
        bucketBase[b] = base;
        int run = base;
        const int4* hp = (const int4*)(histM + b * nBlk);
        int4* op = (int4*)(offs + b * nBlk);
        for (int k = 0; k < nBlk / 4; ++k) {
            int4 h4 = hp[k];
            int4 o4;
            o4.x = run; run += h4.x;
            o4.y = run; run += h4.y;
            o4.z = run; run += h4.z;
            o4.w = run; run += h4.w;
            op[k] = o4;
        }
    }
    if (b == 0) bucketBase[nBuck] = nEdges;
}

// ---- sort stage 3: partition into coarse buckets, line-dense runs ----
__global__ void part_kernel(const int* __restrict__ src, const int* __restrict__ dst,
                            const int* __restrict__ et, const float* __restrict__ norm,
                            const int* __restrict__ offs, uint2* __restrict__ staged,
                            int nEdges, int nBuck, int chunk) {
    __shared__ int cur[512];
    for (int t = threadIdx.x; t < nBuck; t += 256)
        cur[t] = offs[t * PBLK + blockIdx.x];
    __syncthreads();
    int start = blockIdx.x * chunk;
    int end = min(nEdges, start + chunk);
    for (int i = start + threadIdx.x; i < end; i += 256) {
        int d = dst[i];
        int b = d >> BSH;
        int p = atomicAdd(&cur[b], 1);
        staged[p] = make_uint2(((unsigned)(d & 511) << 21) |
                               ((unsigned)src[i] << 3) | (unsigned)et[i],
                               __float_as_uint(norm[i]));
    }
}

// ---- sort stage 4: per-bucket exact sort in LDS; in-place meta rewrite + endOff ----
__global__ void sortB_kernel(uint2* __restrict__ meta, const int* __restrict__ bucketBase,
                             int* __restrict__ endOff, int nNodes) {
    const int b = blockIdx.x;
    const int tid = threadIdx.x;
    const int e0 = bucketBase[b];
    const int n = min(bucketBase[b + 1] - e0, BCAP);
    __shared__ uint2 st[BCAP];
    __shared__ int h[512];
    __shared__ int pb[256];
    h[2 * tid] = 0; h[2 * tid + 1] = 0;
    __syncthreads();
    for (int j = tid; j < n; j += 256) {
        uint2 v = meta[e0 + j];
        st[j] = v;
        atomicAdd(&h[v.x >> 21], 1);
    }
    __syncthreads();
    int h0 = h[2 * tid], h1v = h[2 * tid + 1];
    int ps = h0 + h1v;
    pb[tid] = ps;
    __syncthreads();
    for (int s = 1; s < 256; s <<= 1) {
        int t = (tid >= s) ? pb[tid - s] : 0;
        __syncthreads();
        pb[tid] += t;
        __syncthreads();
    }
    int ex = pb[tid] - ps;     // exclusive pair base
    int d0 = b << BSH;
    int dA = d0 + 2 * tid, dB = dA + 1;
    if (dA < nNodes) endOff[dA] = e0 + ex + h0;
    if (dB < nNodes) endOff[dB] = e0 + ex + ps;
    h[2 * tid] = ex;
    h[2 * tid + 1] = ex + h0;
    __syncthreads();
    for (int j = tid; j < n; j += 256) {
        uint2 v = st[j];
        int r = atomicAdd(&h[v.x >> 21], 1);
        meta[e0 + r] = make_uint2(v.x & 0x1FFFFFu, v.y);
    }
}

// ---- fused layer: aggregate-then-transform. One wave owns 16 dsts.
// Walk dst-sorted edges (scalar spine, 8-deep gather pipeline): lane = k-dim,
// acc[rel] += norm * x[src][lane] via wave-uniform switch. Flush each dst's
// 8x64 fp32 acc to a [16][512] bf16 LDS A-block (row stride 520 to dodge bank
// conflicts). Epilogue: 16 ds_read_b128 + 16*NT MFMAs against fused-K W frags,
// add bias, write output rows once. No Y intermediate, no atomics.
template <int OUT, typename OutT>
__global__ __launch_bounds__(256, 2) void fused_kernel(
    const ushort* __restrict__ xb, const short* __restrict__ Wf,
    const uint2* __restrict__ meta, const int* __restrict__ endOff,
    const float* __restrict__ bias, OutT* __restrict__ out, int nNodes) {
    constexpr int NT = OUT / 16;
    __shared__ ushort ab[4][16][520];
    const int lane = threadIdx.x & 63;
    const int wslot = threadIdx.x >> 6;
    const int wid = blockIdx.x * 4 + wslot;
    const int d0 = wid * 16;
    if (d0 >= nNodes) return;
    const int d1 = min(d0 + 16, nNodes);
    const int ml = lane & 15, kg = lane >> 4;

    int bndv = 0x7fffffff;
    if (lane < 16) bndv = endOff[min(d0 + lane, nNodes - 1)];
    const int eEnd = __builtin_amdgcn_readlane(bndv, d1 - 1 - d0);
    int e = __builtin_amdgcn_readfirstlane((d0 == 0) ? 0 : endOff[d0 - 1]);
    int dcur = d0;
    int bnd = __builtin_amdgcn_readlane(bndv, 0);

    float a[8] = {0.f, 0.f, 0.f, 0.f, 0.f, 0.f, 0.f, 0.f};

    auto flushd = [&]() {
        int dl = dcur - d0;
        ushort* row = &ab[wslot][dl][0];
#pragma unroll
        for (int r = 0; r < 8; ++r) {
            row[r * 64 + lane] = (ushort)bfc(a[r]);
            a[r] = 0.f;
        }
        ++dcur;
        bnd = __builtin_amdgcn_readlane(bndv, min(dcur - d0, 15));
    };
    auto gx = [&](unsigned key) -> ushort {
        return xb[(size_t)(key >> 3) * 64 + lane];
    };
    auto consume = [&](uint2 M, ushort xv_) {
        while (e >= bnd) flushd();
        float xv = bf2f(xv_);
        float nm = __uint_as_float(M.y);
        switch (M.x & 7u) {     // wave-uniform (meta via scalar spine)
            case 0: a[0] = fmaf(nm, xv, a[0]); break;
            case 1: a[1] = fmaf(nm, xv, a[1]); break;
            case 2: a[2] = fmaf(nm, xv, a[2]); break;
            case 3: a[3] = fmaf(nm, xv, a[3]); break;
            case 4: a[4] = fmaf(nm, xv, a[4]); break;
            case 5: a[5] = fmaf(nm, xv, a[5]); break;
            case 6: a[6] = fmaf(nm, xv, a[6]); break;
            case 7: a[7] = fmaf(nm, xv, a[7]); break;
        }
        ++e;
    };

    if (e < eEnd) {
        const int eL = eEnd - 1;
        uint2 Ma[8], Mb[8];
        ushort Va[8];
#pragma unroll
        for (int k = 0; k < 8; ++k) Ma[k] = meta[min(e + k, eL)];
#pragma unroll
        for (int k = 0; k < 8; ++k) Mb[k] = meta[min(e + 8 + k, eL)];
#pragma unroll
        for (int k = 0; k < 8; ++k) Va[k] = gx(Ma[k].x);

        const int nFull = (eEnd - e) >> 3;
        for (int blk = 0; blk < nFull; ++blk) {
            ushort Vb[8];
            uint2 Mc[8];
#pragma unroll
            for (int k = 0; k < 8; ++k) Vb[k] = gx(Mb[k].x);      // gathers blk+1
#pragma unroll
            for (int k = 0; k < 8; ++k) Mc[k] = meta[min(e + 16 + k, eL)];
#pragma unroll
            for (int k = 0; k < 8; ++k) consume(Ma[k], Va[k]);
#pragma unroll
            for (int k = 0; k < 8; ++k) { Ma[k] = Mb[k]; Mb[k] = Mc[k]; Va[k] = Vb[k]; }
        }
        const int rem = eEnd - e;
#pragma unroll
        for (int k = 0; k < 8; ++k)
            if (k < rem) consume(Ma[k], Va[k]);
    }
    while (dcur < d1) flushd();

    // ---- transform epilogue: D[16 dst][OUT] = A[16][512] @ W[512][OUT] + bias ----
    float bv[NT];
#pragma unroll
    for (int nt = 0; nt < NT; ++nt) bv[nt] = bias[nt * 16 + ml];
    f32x4 acc[NT];
#pragma unroll
    for (int nt = 0; nt < NT; ++nt) acc[nt] = (f32x4){0.f, 0.f, 0.f, 0.f};
#pragma unroll
    for (int ks = 0; ks < 16; ++ks) {
        short8v A = *(const short8v*)&ab[wslot][ml][ks * 32 + kg * 8];
        const short* wp = Wf + ((size_t)(ks * NT) * 64 + lane) * 8;
#pragma unroll
        for (int nt = 0; nt < NT; ++nt) {
            short8v B = *(const short8v*)(wp + nt * 512);
            acc[nt] = __builtin_amdgcn_mfma_f32_16x16x32_bf16(A, B, acc[nt], 0, 0, 0);
        }
    }
#pragma unroll
    for (int nt = 0; nt < NT; ++nt) {
#pragma unroll
        for (int i = 0; i < 4; ++i) {
            int d = d0 + kg * 4 + i;
            if (d < nNodes) {
                float v = acc[nt][i] + bv[nt];
                if constexpr (sizeof(OutT) == 2)
                    out[(size_t)d * OUT + nt * 16 + ml] = (OutT)(ushort)bfc(v);
                else
                    out[(size_t)d * OUT + nt * 16 + ml] = (OutT)v;
            }
        }
    }
}

extern "C" void kernel_launch(void* const* d_in, const int* in_sizes, int n_in,
                              void* d_out, int out_size, void* d_ws, size_t ws_size,
                              hipStream_t stream) {
    const float* emb    = (const float*)d_in[0];
    const float* basis1 = (const float*)d_in[1];
    const float* comp1  = (const float*)d_in[2];
    const float* bias1  = (const float*)d_in[3];
    const float* basis2 = (const float*)d_in[4];
    const float* comp2  = (const float*)d_in[5];
    const float* bias2  = (const float*)d_in[6];
    const int*   src    = (const int*)d_in[7];
    const int*   dst    = (const int*)d_in[8];
    const int*   etype  = (const int*)d_in[9];
    const float* norm   = (const float*)d_in[10];
    float* out = (float*)d_out;

    const int nNodes = in_sizes[0] / 64;   // 200000
    const int nEdges = in_sizes[7];        // 1000000

    const int nBuck = (nNodes + 511) >> BSH;            // 391
    const int chunk = (nEdges + PBLK - 1) / PBLK;       // 3907

    char* ws = (char*)d_ws;
    short* Wf1        = (short*)(ws);                               // 64 KB
    short* Wf2        = (short*)(ws + 65536);                       // 32 KB
    int*   histM      = (int*)(ws + 98304);                         // 400,384 B
    int*   offs       = (int*)(ws + 498688);                        // 400,384 B
    int*   bucketBase = (int*)(ws + 899072);                        // 1,568 B
    int*   endOff     = (int*)(ws + 900640);                        // 800,000 B
    size_t offMeta = 1703936;
    uint2* meta       = (uint2*)(ws + offMeta);                     // 8 MB
    size_t offX = offMeta + (size_t)nEdges * 8;                     // 9,703,936
    ushort* embb = (ushort*)(ws + offX);                            // 25.6 MB
    ushort* h1b  = (ushort*)(ws + offX + (size_t)nNodes * 64 * 2);  // 25.6 MB

    // ---- prep: W frags, bf16 emb, dst-sort (all verified components) ----
    wprep_kernel<<<192, 256, 0, stream>>>(basis1, comp1, basis2, comp2, Wf1, Wf2);
    cvt_kernel<<<1024, 256, 0, stream>>>(emb, embb, nNodes * 16);
    histA_kernel<<<PBLK, 256, 0, stream>>>(dst, histM, nEdges, nBuck, chunk);
    scanA_kernel<<<1, 512, 0, stream>>>(histM, offs, bucketBase, nBuck, PBLK, nEdges);
    part_kernel<<<PBLK, 256, 0, stream>>>(src, dst, etype, norm, offs, meta,
                                          nEdges, nBuck, chunk);
    sortB_kernel<<<nBuck, 256, 0, stream>>>(meta, bucketBase, endOff, nNodes);

    // ---- fused layers: aggregate-then-transform, 16 dsts/wave ----
    const int nWaves = (nNodes + 15) / 16;              // 12500
    const int fBlocks = (nWaves + 3) / 4;               // 3125
    fused_kernel<64, ushort><<<fBlocks, 256, 0, stream>>>(
        embb, Wf1, meta, endOff, bias1, h1b, nNodes);
    fused_kernel<32, float><<<fBlocks, 256, 0, stream>>>(
        h1b, Wf2, meta, endOff, bias2, out, nNodes);
}

// Round 16
// 217.924 us; speedup vs baseline: 1.6657x; 1.6657x over previous
//
#include <hip/hip_runtime.h>
#include <hip/hip_bf16.h>

#define NRELS 8
#define NB 8
#define PBLK 256          // partition blocks
#define BSH 9             // dsts per bucket = 512
#define BCAP 3584         // max edges per bucket staged in LDS

typedef __attribute__((ext_vector_type(8))) short short8v;
typedef __attribute__((ext_vector_type(4))) float f32x4;

__device__ __forceinline__ short bfc(float f) {
    __hip_bfloat16 h = __float2bfloat16(f);
    return *reinterpret_cast<short*>(&h);
}
__device__ __forceinline__ float bf2f(ushort u) {
    return __uint_as_float((unsigned)u << 16);
}

// ---- W in fused-K MFMA B-frag order (verified R14). K = 512 = (rel, k64).
// frag (ks, nt): lane holds W[k512 = ks*32 + (lane>>4)*8 + j][c = nt*16 + (lane&15)].
__global__ void wprep_kernel(const float* __restrict__ basis1, const float* __restrict__ comp1,
                             const float* __restrict__ basis2, const float* __restrict__ comp2,
                             short* __restrict__ Wf1, short* __restrict__ Wf2) {
    int idx = blockIdx.x * blockDim.x + threadIdx.x;
    const int n1 = 16 * 4 * 64 * 8;   // 32768
    const int n2 = 16 * 2 * 64 * 8;   // 16384
    if (idx < n1) {
        int j = idx & 7, lane = (idx >> 3) & 63, nt = (idx >> 9) & 3, ks = idx >> 11;
        int k512 = ks * 32 + (lane >> 4) * 8 + j;
        int r = k512 >> 6, k64 = k512 & 63;
        int c = nt * 16 + (lane & 15);
        float s = 0.f;
#pragma unroll
        for (int b = 0; b < NB; ++b)
            s = fmaf(comp1[r * NB + b], basis1[b * 4096 + k64 * 64 + c], s);
        Wf1[idx] = bfc(s);
    } else if (idx < n1 + n2) {
        int i2 = idx - n1;
        int j = i2 & 7, lane = (i2 >> 3) & 63, nt = (i2 >> 9) & 1, ks = i2 >> 10;
        int k512 = ks * 32 + (lane >> 4) * 8 + j;
        int r = k512 >> 6, k64 = k512 & 63;
        int c = nt * 16 + (lane & 15);
        float s = 0.f;
#pragma unroll
        for (int b = 0; b < NB; ++b)
            s = fmaf(comp2[r * NB + b], basis2[b * 2048 + k64 * 32 + c], s);
        Wf2[i2] = bfc(s);
    }
}

// fp32 -> bf16 (vector x4)
__global__ void cvt_kernel(const float* __restrict__ in, ushort* __restrict__ outb, int n4) {
    for (int i = blockIdx.x * blockDim.x + threadIdx.x; i < n4;
         i += gridDim.x * blockDim.x) {
        float4 v = reinterpret_cast<const float4*>(in)[i];
        ushort4 o;
        o.x = (ushort)bfc(v.x); o.y = (ushort)bfc(v.y);
        o.z = (ushort)bfc(v.z); o.w = (ushort)bfc(v.w);
        reinterpret_cast<ushort4*>(outb)[i] = o;
    }
}

// ---- sort stage 1: per-block coarse histogram; histM layout [bucket][block] ----
__global__ void histA_kernel(const int* __restrict__ dst, int* __restrict__ histM,
                             int nEdges, int nBuck, int chunk) {
    __shared__ int h[512];
    for (int t = threadIdx.x; t < nBuck; t += 256) h[t] = 0;
    __syncthreads();
    int start = blockIdx.x * chunk;
    int end = min(nEdges, start + chunk);
    for (int i = start + threadIdx.x; i < end; i += 256)
        atomicAdd(&h[dst[i] >> BSH], 1);
    __syncthreads();
    for (int t = threadIdx.x; t < nBuck; t += 256)
        histM[t * PBLK + blockIdx.x] = h[t];
}

// ---- sort stage 2 (R12-verified): totals scan -> bucketBase + per-(bucket,block) offs ----
__global__ void scanA_kernel(const int* __restrict__ histM, int* __restrict__ offs,
                             int* __restrict__ bucketBase, int nBuck, int nBlk, int nEdges) {
    __shared__ int tot[512];
    const int b = threadIdx.x;
    int s = 0;
    if (b < nBuck) {
        const int4* hp = (const int4*)(histM + b * nBlk);
        for (int k = 0; k < nBlk / 4; ++k) {
            int4 v = hp[k];
            s += v.x + v.y + v.z + v.w;
        }
    }
    tot[b] = s;
    __syncthreads();
    int own = s;
    for (int st = 1; st < 512; st <<= 1) {
        int t = (b >= st) ? tot[b - st] : 0;
        __syncthreads();
        tot[b] += t;
        __syncthreads();
    }
    int base = tot[b] - own;   // exclusive
    if (b < nBuck) {
        bucketBase[b] = base;
        int run = base;
        const int4* hp = (const int4*)(histM + b * nBlk);
        int4* op = (int4*)(offs + b * nBlk);
        for (int k = 0; k < nBlk / 4; ++k) {
            int4 h4 = hp[k];
            int4 o4;
            o4.x = run; run += h4.x;
            o4.y = run; run += h4.y;
            o4.z = run; run += h4.z;
            o4.w = run; run += h4.w;
            op[k] = o4;
        }
    }
    if (b == 0) bucketBase[nBuck] = nEdges;
}

// ---- sort stage 3: partition into coarse buckets, line-dense runs ----
__global__ void part_kernel(const int* __restrict__ src, const int* __restrict__ dst,
                            const int* __restrict__ et, const float* __restrict__ norm,
                            const int* __restrict__ offs, uint2* __restrict__ staged,
                            int nEdges, int nBuck, int chunk) {
    __shared__ int cur[512];
    for (int t = threadIdx.x; t < nBuck; t += 256)
        cur[t] = offs[t * PBLK + blockIdx.x];
    __syncthreads();
    int start = blockIdx.x * chunk;
    int end = min(nEdges, start + chunk);
    for (int i = start + threadIdx.x; i < end; i += 256) {
        int d = dst[i];
        int b = d >> BSH;
        int p = atomicAdd(&cur[b], 1);
        staged[p] = make_uint2(((unsigned)(d & 511) << 21) |
                               ((unsigned)src[i] << 3) | (unsigned)et[i],
                               __float_as_uint(norm[i]));
    }
}

// ---- sort stage 4: per-bucket sort by dstlocal in LDS; meta rewrite + endOff ----
__global__ void sortB_kernel(uint2* __restrict__ meta, const int* __restrict__ bucketBase,
                             int* __restrict__ endOff, int nNodes) {
    const int b = blockIdx.x;
    const int tid = threadIdx.x;
    const int e0 = bucketBase[b];
    const int n = min(bucketBase[b + 1] - e0, BCAP);
    __shared__ uint2 st[BCAP];
    __shared__ int h[512];
    __shared__ int pb[256];
    h[2 * tid] = 0; h[2 * tid + 1] = 0;
    __syncthreads();
    for (int j = tid; j < n; j += 256) {
        uint2 v = meta[e0 + j];
        st[j] = v;
        atomicAdd(&h[v.x >> 21], 1);
    }
    __syncthreads();
    int h0 = h[2 * tid], h1v = h[2 * tid + 1];
    int ps = h0 + h1v;
    pb[tid] = ps;
    __syncthreads();
    for (int s = 1; s < 256; s <<= 1) {
        int t = (tid >= s) ? pb[tid - s] : 0;
        __syncthreads();
        pb[tid] += t;
        __syncthreads();
    }
    int ex = pb[tid] - ps;     // exclusive pair base
    int d0 = b << BSH;
    int dA = d0 + 2 * tid, dB = dA + 1;
    if (dA < nNodes) endOff[dA] = e0 + ex + h0;
    if (dB < nNodes) endOff[dB] = e0 + ex + ps;
    h[2 * tid] = ex;
    h[2 * tid + 1] = ex + h0;
    __syncthreads();
    for (int j = tid; j < n; j += 256) {
        uint2 v = st[j];
        int r = atomicAdd(&h[v.x >> 21], 1);
        meta[e0 + r] = make_uint2(v.x & 0x1FFFFFu, v.y);
    }
}

// ---- fused layer v2.1: aggregate-then-transform, block-shared A-tile.
// Block owns 16 dsts; wave w aggregates dsts [d0blk+4w, +4): scalar spine walks
// dst-sorted edges, ONE fp32 acc/lane (lane = k64). On scalar rel/dst change the
// run is flushed into LDS A[dst][rel*64+k] with READ-MODIFY-WRITE accumulate
// (FIX vs R15: relations recur in multiple runs within a dst — plain store
// overwrote earlier runs; rows are pre-zeroed so RMW is exact up to bf16).
// Epilogue (R14-verified): wave nt computes D[16][16] quadrant via 16 MFMAs.
template <int OUT, typename OutT>
__global__ __launch_bounds__(256, 4) void fused_kernel(
    const ushort* __restrict__ xb, const short* __restrict__ Wf,
    const uint2* __restrict__ meta, const int* __restrict__ endOff,
    const float* __restrict__ bias, OutT* __restrict__ out, int nNodes) {
    constexpr int NT = OUT / 16;
    __shared__ ushort ab[16][520];
    const int lane = threadIdx.x & 63;
    const int wslot = threadIdx.x >> 6;
    const int d0blk = blockIdx.x * 16;
    const int d0 = d0blk + wslot * 4;
    const int rowBase = wslot * 4;

    // zero own 4 rows (cols 0..511; pad unread by MFMA)
    {
        ushort4 z4 = {0, 0, 0, 0};
#pragma unroll
        for (int r = 0; r < 4; ++r) {
            *(ushort4*)&ab[rowBase + r][lane * 4] = z4;
            *(ushort4*)&ab[rowBase + r][256 + lane * 4] = z4;
        }
    }

    if (d0 < nNodes) {
        const int d1 = min(d0 + 4, nNodes);
        int bndv = 0x7fffffff;
        if (lane < 4) bndv = endOff[min(d0 + lane, nNodes - 1)];
        const int eEnd = __builtin_amdgcn_readlane(bndv, d1 - 1 - d0);
        int e = __builtin_amdgcn_readfirstlane((d0 == 0) ? 0 : endOff[d0 - 1]);
        int dl = 0;
        int bnd = __builtin_amdgcn_readlane(bndv, 0);
        float acc = 0.f;
        int curRel = -1;

        auto flushRel = [&]() {
            if (curRel >= 0) {
                ushort* p = &ab[rowBase + dl][curRel * 64 + lane];
                *p = (ushort)bfc(bf2f(*p) + acc);      // accumulate across runs
                acc = 0.f;
            }
            curRel = -1;
        };
        auto nextDst = [&]() {
            flushRel();
            ++dl;
            bnd = __builtin_amdgcn_readlane(bndv, min(dl, 3));
        };
        auto gx = [&](unsigned key) -> ushort {
            return xb[(size_t)(key >> 3) * 64 + lane];
        };
        auto consume = [&](uint2 M, ushort xv_) {
            while (e >= bnd) nextDst();
            int r = (int)(M.x & 7u);          // scalar (meta via uniform s_load)
            if (r != curRel) { flushRel(); curRel = r; }
            acc = fmaf(__uint_as_float(M.y), bf2f(xv_), acc);
            ++e;
        };

        if (e < eEnd) {
            const int eL = eEnd - 1;
            uint2 Ma[8], Mb[8];
            ushort Va[8];
#pragma unroll
            for (int k = 0; k < 8; ++k) Ma[k] = meta[min(e + k, eL)];
#pragma unroll
            for (int k = 0; k < 8; ++k) Mb[k] = meta[min(e + 8 + k, eL)];
#pragma unroll
            for (int k = 0; k < 8; ++k) Va[k] = gx(Ma[k].x);

            const int nFull = (eEnd - e) >> 3;
            for (int blk = 0; blk < nFull; ++blk) {
                ushort Vb[8];
                uint2 Mc[8];
#pragma unroll
                for (int k = 0; k < 8; ++k) Vb[k] = gx(Mb[k].x);      // gathers blk+1
#pragma unroll
                for (int k = 0; k < 8; ++k) Mc[k] = meta[min(e + 16 + k, eL)];
#pragma unroll
                for (int k = 0; k < 8; ++k) consume(Ma[k], Va[k]);
#pragma unroll
                for (int k = 0; k < 8; ++k) { Ma[k] = Mb[k]; Mb[k] = Mc[k]; Va[k] = Vb[k]; }
            }
            const int rem = eEnd - e;
#pragma unroll
            for (int k = 0; k < 8; ++k)
                if (k < rem) consume(Ma[k], Va[k]);
        }
        while (dl < 4) nextDst();
    }
    __syncthreads();

    // ---- transform epilogue: wave nt computes D[16 dst][16 col] quadrant ----
    if (wslot < NT) {
        const int ml = lane & 15, kg = lane >> 4;
        const int nt = wslot;
        f32x4 acc4 = (f32x4){0.f, 0.f, 0.f, 0.f};
#pragma unroll
        for (int ks = 0; ks < 16; ++ks) {
            short8v A = *(const short8v*)&ab[ml][ks * 32 + kg * 8];
            short8v B = *(const short8v*)(Wf + ((size_t)(ks * NT + nt) * 64 + lane) * 8);
            acc4 = __builtin_amdgcn_mfma_f32_16x16x32_bf16(A, B, acc4, 0, 0, 0);
        }
        float bvv = bias[nt * 16 + ml];
#pragma unroll
        for (int i = 0; i < 4; ++i) {
            int d = d0blk + kg * 4 + i;
            if (d < nNodes) {
                float v = acc4[i] + bvv;
                if constexpr (sizeof(OutT) == 2)
                    out[(size_t)d * OUT + nt * 16 + ml] = (OutT)(ushort)bfc(v);
                else
                    out[(size_t)d * OUT + nt * 16 + ml] = (OutT)v;
            }
        }
    }
}

extern "C" void kernel_launch(void* const* d_in, const int* in_sizes, int n_in,
                              void* d_out, int out_size, void* d_ws, size_t ws_size,
                              hipStream_t stream) {
    const float* emb    = (const float*)d_in[0];
    const float* basis1 = (const float*)d_in[1];
    const float* comp1  = (const float*)d_in[2];
    const float* bias1  = (const float*)d_in[3];
    const float* basis2 = (const float*)d_in[4];
    const float* comp2  = (const float*)d_in[5];
    const float* bias2  = (const float*)d_in[6];
    const int*   src    = (const int*)d_in[7];
    const int*   dst    = (const int*)d_in[8];
    const int*   etype  = (const int*)d_in[9];
    const float* norm   = (const float*)d_in[10];
    float* out = (float*)d_out;

    const int nNodes = in_sizes[0] / 64;   // 200000
    const int nEdges = in_sizes[7];        // 1000000

    const int nBuck = (nNodes + 511) >> BSH;            // 391
    const int chunk = (nEdges + PBLK - 1) / PBLK;       // 3907

    char* ws = (char*)d_ws;
    short* Wf1        = (short*)(ws);                               // 64 KB
    short* Wf2        = (short*)(ws + 65536);                       // 32 KB
    int*   histM      = (int*)(ws + 98304);                         // 400,384 B
    int*   offs       = (int*)(ws + 498688);                        // 400,384 B
    int*   bucketBase = (int*)(ws + 899072);                        // 1,568 B
    int*   endOff     = (int*)(ws + 900640);                        // 800,000 B
    size_t offMeta = 1703936;
    uint2* meta       = (uint2*)(ws + offMeta);                     // 8 MB
    size_t offX = offMeta + (size_t)nEdges * 8;                     // 9,703,936
    ushort* embb = (ushort*)(ws + offX);                            // 25.6 MB
    ushort* h1b  = (ushort*)(ws + offX + (size_t)nNodes * 64 * 2);  // 25.6 MB

    // ---- prep: W frags, bf16 emb, dst-sort (all verified components) ----
    wprep_kernel<<<192, 256, 0, stream>>>(basis1, comp1, basis2, comp2, Wf1, Wf2);
    cvt_kernel<<<1024, 256, 0, stream>>>(emb, embb, nNodes * 16);
    histA_kernel<<<PBLK, 256, 0, stream>>>(dst, histM, nEdges, nBuck, chunk);
    scanA_kernel<<<1, 512, 0, stream>>>(histM, offs, bucketBase, nBuck, PBLK, nEdges);
    part_kernel<<<PBLK, 256, 0, stream>>>(src, dst, etype, norm, offs, meta,
                                          nEdges, nBuck, chunk);
    sortB_kernel<<<nBuck, 256, 0, stream>>>(meta, bucketBase, endOff, nNodes);

    // ---- fused layers: 16 dsts/block (4 per wave), block-shared A-tile ----
    const int fBlocks = (nNodes + 15) / 16;             // 12500
    fused_kernel<64, ushort><<<fBlocks, 256, 0, stream>>>(
        embb, Wf1, meta, endOff, bias1, h1b, nNodes);
    fused_kernel<32, float><<<fBlocks, 256, 0, stream>>>(
        h1b, Wf2, meta, endOff, bias2, out, nNodes);
}

// Round 17
// 211.408 us; speedup vs baseline: 1.7171x; 1.0308x over previous
//
#include <hip/hip_runtime.h>
#include <hip/hip_bf16.h>

#define NRELS 8
#define NB 8
#define PBLK 256          // partition blocks
#define BSH 9             // dsts per bucket = 512
#define BCAP 3584         // max edges per bucket staged in LDS

typedef __attribute__((ext_vector_type(8))) short short8v;
typedef __attribute__((ext_vector_type(4))) float f32x4;

__device__ __forceinline__ short bfc(float f) {
    __hip_bfloat16 h = __float2bfloat16(f);
    return *reinterpret_cast<short*>(&h);
}
__device__ __forceinline__ float bf2f(ushort u) {
    return __uint_as_float((unsigned)u << 16);
}

// ---- W in fused-K MFMA B-frag order (verified R14/R16). K = 512 = (rel, k64).
// frag (ks, nt): lane holds W[k512 = ks*32 + (lane>>4)*8 + j][c = nt*16 + (lane&15)].
__global__ void wprep_kernel(const float* __restrict__ basis1, const float* __restrict__ comp1,
                             const float* __restrict__ basis2, const float* __restrict__ comp2,
                             short* __restrict__ Wf1, short* __restrict__ Wf2) {
    int idx = blockIdx.x * blockDim.x + threadIdx.x;
    const int n1 = 16 * 4 * 64 * 8;   // 32768
    const int n2 = 16 * 2 * 64 * 8;   // 16384
    if (idx < n1) {
        int j = idx & 7, lane = (idx >> 3) & 63, nt = (idx >> 9) & 3, ks = idx >> 11;
        int k512 = ks * 32 + (lane >> 4) * 8 + j;
        int r = k512 >> 6, k64 = k512 & 63;
        int c = nt * 16 + (lane & 15);
        float s = 0.f;
#pragma unroll
        for (int b = 0; b < NB; ++b)
            s = fmaf(comp1[r * NB + b], basis1[b * 4096 + k64 * 64 + c], s);
        Wf1[idx] = bfc(s);
    } else if (idx < n1 + n2) {
        int i2 = idx - n1;
        int j = i2 & 7, lane = (i2 >> 3) & 63, nt = (i2 >> 9) & 1, ks = i2 >> 10;
        int k512 = ks * 32 + (lane >> 4) * 8 + j;
        int r = k512 >> 6, k64 = k512 & 63;
        int c = nt * 16 + (lane & 15);
        float s = 0.f;
#pragma unroll
        for (int b = 0; b < NB; ++b)
            s = fmaf(comp2[r * NB + b], basis2[b * 2048 + k64 * 32 + c], s);
        Wf2[i2] = bfc(s);
    }
}

// fp32 -> bf16 (vector x4)
__global__ void cvt_kernel(const float* __restrict__ in, ushort* __restrict__ outb, int n4) {
    for (int i = blockIdx.x * blockDim.x + threadIdx.x; i < n4;
         i += gridDim.x * blockDim.x) {
        float4 v = reinterpret_cast<const float4*>(in)[i];
        ushort4 o;
        o.x = (ushort)bfc(v.x); o.y = (ushort)bfc(v.y);
        o.z = (ushort)bfc(v.z); o.w = (ushort)bfc(v.w);
        reinterpret_cast<ushort4*>(outb)[i] = o;
    }
}

// ---- sort stage 1: per-block coarse histogram; histM layout [bucket][block] ----
__global__ void histA_kernel(const int* __restrict__ dst, int* __restrict__ histM,
                             int nEdges, int nBuck, int chunk) {
    __shared__ int h[512];
    for (int t = threadIdx.x; t < nBuck; t += 256) h[t] = 0;
    __syncthreads();
    int start = blockIdx.x * chunk;
    int end = min(nEdges, start + chunk);
    for (int i = start + threadIdx.x; i < end; i += 256)
        atomicAdd(&h[dst[i] >> BSH], 1);
    __syncthreads();
    for (int t = threadIdx.x; t < nBuck; t += 256)
        histM[t * PBLK + blockIdx.x] = h[t];
}

// ---- sort stage 2 (R12-verified): totals scan -> bucketBase + per-(bucket,block) offs ----
__global__ void scanA_kernel(const int* __restrict__ histM, int* __restrict__ offs,
                             int* __restrict__ bucketBase, int nBuck, int nBlk, int nEdges) {
    __shared__ int tot[512];
    const int b = threadIdx.x;
    int s = 0;
    if (b < nBuck) {
        const int4* hp = (const int4*)(histM + b * nBlk);
        for (int k = 0; k < nBlk / 4; ++k) {
            int4 v = hp[k];
            s += v.x + v.y + v.z + v.w;
        }
    }
    tot[b] = s;
    __syncthreads();
    int own = s;
    for (int st = 1; st < 512; st <<= 1) {
        int t = (b >= st) ? tot[b - st] : 0;
        __syncthreads();
        tot[b] += t;
        __syncthreads();
    }
    int base = tot[b] - own;   // exclusive
    if (b < nBuck) {
        bucketBase[b] = base;
        int run = base;
        const int4* hp = (const int4*)(histM + b * nBlk);
        int4* op = (int4*)(offs + b * nBlk);
        for (int k = 0; k < nBlk / 4; ++k) {
            int4 h4 = hp[k];
            int4 o4;
            o4.x = run; run += h4.x;
            o4.y = run; run += h4.y;
            o4.z = run; run += h4.z;
            o4.w = run; run += h4.w;
            op[k] = o4;
        }
    }
    if (b == 0) bucketBase[nBuck] = nEdges;
}

// ---- sort stage 3: partition into coarse buckets, line-dense runs ----
__global__ void part_kernel(const int* __restrict__ src, const int* __restrict__ dst,
                            const int* __restrict__ et, const float* __restrict__ norm,
                            const int* __restrict__ offs, uint2* __restrict__ staged,
                            int nEdges, int nBuck, int chunk) {
    __shared__ int cur[512];
    for (int t = threadIdx.x; t < nBuck; t += 256)
        cur[t] = offs[t * PBLK + blockIdx.x];
    __syncthreads();
    int start = blockIdx.x * chunk;
    int end = min(nEdges, start + chunk);
    for (int i = start + threadIdx.x; i < end; i += 256) {
        int d = dst[i];
        int b = d >> BSH;
        int p = atomicAdd(&cur[b], 1);
        staged[p] = make_uint2(((unsigned)(d & 511) << 21) |
                               ((unsigned)src[i] << 3) | (unsigned)et[i],
                               __float_as_uint(norm[i]));
    }
}

// ---- sort stage 4 v2: per-bucket sort by (dstlocal, rel) — 4096 bins in LDS.
// Each (dst, rel) pair becomes exactly ONE contiguous run -> fused kernel can
// plain-store flushes (no LDS RMW). Hist padded +1 word per 16 bins so the
// per-thread 16-bin stride doesn't alias to 2 banks. endOff captured at each
// dst's 8-bin boundary. Meta rewritten in place, dstlocal stripped.
__global__ void sortB_kernel(uint2* __restrict__ meta, const int* __restrict__ bucketBase,
                             int* __restrict__ endOff, int nNodes) {
    const int b = blockIdx.x;
    const int tid = threadIdx.x;
    const int e0 = bucketBase[b];
    const int n = min(bucketBase[b + 1] - e0, BCAP);
    __shared__ uint2 st[BCAP];      // 28,672 B
    __shared__ int h[4352];         // 4096 bins + pad (f(bin) = bin + bin/16)
    __shared__ int pb[256];
#pragma unroll
    for (int k = 0; k < 16; ++k) h[tid * 17 + k] = 0;   // f(tid*16+k) = tid*17+k
    __syncthreads();
    for (int j = tid; j < n; j += 256) {
        uint2 v = meta[e0 + j];
        st[j] = v;
        int key = (int)((v.x >> 21) << 3) | (int)(v.x & 7u);
        atomicAdd(&h[key + (key >> 4)], 1);
    }
    __syncthreads();
    int loc[16];
    int s = 0;
#pragma unroll
    for (int k = 0; k < 16; ++k) { loc[k] = h[tid * 17 + k]; s += loc[k]; }
    pb[tid] = s;
    __syncthreads();
    for (int stp = 1; stp < 256; stp <<= 1) {
        int t = (tid >= stp) ? pb[tid - stp] : 0;
        __syncthreads();
        pb[tid] += t;
        __syncthreads();
    }
    int run = pb[tid] - s;          // exclusive base of this thread's 16 bins
    const int d0 = b << BSH;
#pragma unroll
    for (int k = 0; k < 16; ++k) {
        h[tid * 17 + k] = run;      // bin cursor (exclusive offset)
        run += loc[k];
        if ((k & 7) == 7) {
            int d = d0 + tid * 2 + (k >> 3);
            if (d < nNodes) endOff[d] = e0 + run;
        }
    }
    __syncthreads();
    for (int j = tid; j < n; j += 256) {
        uint2 v = st[j];
        int key = (int)((v.x >> 21) << 3) | (int)(v.x & 7u);
        int r = atomicAdd(&h[key + (key >> 4)], 1);
        meta[e0 + r] = make_uint2(v.x & 0x1FFFFFu, v.y);
    }
}

// ---- fused layer v3: aggregate-then-transform, block-shared A-tile.
// Block owns 16 dsts; wave w aggregates dsts [d0blk+4w, +4): scalar spine walks
// (dst,rel)-sorted edges, ONE fp32 acc/lane (lane = k64). Each (dst,rel) run is
// unique -> flush is a PLAIN ds_write_b16 into the pre-zeroed A row (no RMW, no
// LDS-read latency on the serial spine). Epilogue (R14/R16-verified): wave nt
// computes the D[16 dst][16 col] quadrant via 16 MFMAs against fused-K W frags.
template <int OUT, typename OutT>
__global__ __launch_bounds__(256, 4) void fused_kernel(
    const ushort* __restrict__ xb, const short* __restrict__ Wf,
    const uint2* __restrict__ meta, const int* __restrict__ endOff,
    const float* __restrict__ bias, OutT* __restrict__ out, int nNodes) {
    constexpr int NT = OUT / 16;
    __shared__ ushort ab[16][520];
    const int lane = threadIdx.x & 63;
    const int wslot = threadIdx.x >> 6;
    const int d0blk = blockIdx.x * 16;
    const int d0 = d0blk + wslot * 4;
    const int rowBase = wslot * 4;

    // zero own 4 rows (cols 0..511; pad unread by MFMA)
    {
        ushort4 z4 = {0, 0, 0, 0};
#pragma unroll
        for (int r = 0; r < 4; ++r) {
            *(ushort4*)&ab[rowBase + r][lane * 4] = z4;
            *(ushort4*)&ab[rowBase + r][256 + lane * 4] = z4;
        }
    }

    if (d0 < nNodes) {
        const int d1 = min(d0 + 4, nNodes);
        int bndv = 0x7fffffff;
        if (lane < 4) bndv = endOff[min(d0 + lane, nNodes - 1)];
        const int eEnd = __builtin_amdgcn_readlane(bndv, d1 - 1 - d0);
        int e = __builtin_amdgcn_readfirstlane((d0 == 0) ? 0 : endOff[d0 - 1]);
        int dl = 0;
        int bnd = __builtin_amdgcn_readlane(bndv, 0);
        float acc = 0.f;
        int curRel = -1;

        auto flushRel = [&]() {
            if (curRel >= 0) {
                ab[rowBase + dl][curRel * 64 + lane] = (ushort)bfc(acc);   // unique run: plain store
                acc = 0.f;
            }
            curRel = -1;
        };
        auto nextDst = [&]() {
            flushRel();
            ++dl;
            bnd = __builtin_amdgcn_readlane(bndv, min(dl, 3));
        };
        auto gx = [&](unsigned key) -> ushort {
            return xb[(size_t)(key >> 3) * 64 + lane];
        };
        auto consume = [&](uint2 M, ushort xv_) {
            while (e >= bnd) nextDst();
            int r = (int)(M.x & 7u);          // scalar (meta via uniform s_load)
            if (r != curRel) { flushRel(); curRel = r; }
            acc = fmaf(__uint_as_float(M.y), bf2f(xv_), acc);
            ++e;
        };

        if (e < eEnd) {
            const int eL = eEnd - 1;
            uint2 Ma[8], Mb[8];
            ushort Va[8];
#pragma unroll
            for (int k = 0; k < 8; ++k) Ma[k] = meta[min(e + k, eL)];
#pragma unroll
            for (int k = 0; k < 8; ++k) Mb[k] = meta[min(e + 8 + k, eL)];
#pragma unroll
            for (int k = 0; k < 8; ++k) Va[k] = gx(Ma[k].x);

            const int nFull = (eEnd - e) >> 3;
            for (int blk = 0; blk < nFull; ++blk) {
                ushort Vb[8];
                uint2 Mc[8];
#pragma unroll
                for (int k = 0; k < 8; ++k) Vb[k] = gx(Mb[k].x);      // gathers blk+1
#pragma unroll
                for (int k = 0; k < 8; ++k) Mc[k] = meta[min(e + 16 + k, eL)];
#pragma unroll
                for (int k = 0; k < 8; ++k) consume(Ma[k], Va[k]);
#pragma unroll
                for (int k = 0; k < 8; ++k) { Ma[k] = Mb[k]; Mb[k] = Mc[k]; Va[k] = Vb[k]; }
            }
            const int rem = eEnd - e;
#pragma unroll
            for (int k = 0; k < 8; ++k)
                if (k < rem) consume(Ma[k], Va[k]);
        }
        while (dl < 4) nextDst();
    }
    __syncthreads();

    // ---- transform epilogue: wave nt computes D[16 dst][16 col] quadrant ----
    if (wslot < NT) {
        const int ml = lane & 15, kg = lane >> 4;
        const int nt = wslot;
        f32x4 acc4 = (f32x4){0.f, 0.f, 0.f, 0.f};
#pragma unroll
        for (int ks = 0; ks < 16; ++ks) {
            short8v A = *(const short8v*)&ab[ml][ks * 32 + kg * 8];
            short8v B = *(const short8v*)(Wf + ((size_t)(ks * NT + nt) * 64 + lane) * 8);
            acc4 = __builtin_amdgcn_mfma_f32_16x16x32_bf16(A, B, acc4, 0, 0, 0);
        }
        float bvv = bias[nt * 16 + ml];
#pragma unroll
        for (int i = 0; i < 4; ++i) {
            int d = d0blk + kg * 4 + i;
            if (d < nNodes) {
                float v = acc4[i] + bvv;
                if constexpr (sizeof(OutT) == 2)
                    out[(size_t)d * OUT + nt * 16 + ml] = (OutT)(ushort)bfc(v);
                else
                    out[(size_t)d * OUT + nt * 16 + ml] = (OutT)v;
            }
        }
    }
}

extern "C" void kernel_launch(void* const* d_in, const int* in_sizes, int n_in,
                              void* d_out, int out_size, void* d_ws, size_t ws_size,
                              hipStream_t stream) {
    const float* emb    = (const float*)d_in[0];
    const float* basis1 = (const float*)d_in[1];
    const float* comp1  = (const float*)d_in[2];
    const float* bias1  = (const float*)d_in[3];
    const float* basis2 = (const float*)d_in[4];
    const float* comp2  = (const float*)d_in[5];
    const float* bias2  = (const float*)d_in[6];
    const int*   src    = (const int*)d_in[7];
    const int*   dst    = (const int*)d_in[8];
    const int*   etype  = (const int*)d_in[9];
    const float* norm   = (const float*)d_in[10];
    float* out = (float*)d_out;

    const int nNodes = in_sizes[0] / 64;   // 200000
    const int nEdges = in_sizes[7];        // 1000000

    const int nBuck = (nNodes + 511) >> BSH;            // 391
    const int chunk = (nEdges + PBLK - 1) / PBLK;       // 3907

    char* ws = (char*)d_ws;
    short* Wf1        = (short*)(ws);                               // 64 KB
    short* Wf2        = (short*)(ws + 65536);                       // 32 KB
    int*   histM      = (int*)(ws + 98304);                         // 400,384 B
    int*   offs       = (int*)(ws + 498688);                        // 400,384 B
    int*   bucketBase = (int*)(ws + 899072);                        // 1,568 B
    int*   endOff     = (int*)(ws + 900640);                        // 800,000 B
    size_t offMeta = 1703936;
    uint2* meta       = (uint2*)(ws + offMeta);                     // 8 MB
    size_t offX = offMeta + (size_t)nEdges * 8;                     // 9,703,936
    ushort* embb = (ushort*)(ws + offX);                            // 25.6 MB
    ushort* h1b  = (ushort*)(ws + offX + (size_t)nNodes * 64 * 2);  // 25.6 MB

    // ---- prep: W frags, bf16 emb, (dst,rel)-sort ----
    wprep_kernel<<<192, 256, 0, stream>>>(basis1, comp1, basis2, comp2, Wf1, Wf2);
    cvt_kernel<<<1024, 256, 0, stream>>>(emb, embb, nNodes * 16);
    histA_kernel<<<PBLK, 256, 0, stream>>>(dst, histM, nEdges, nBuck, chunk);
    scanA_kernel<<<1, 512, 0, stream>>>(histM, offs, bucketBase, nBuck, PBLK, nEdges);
    part_kernel<<<PBLK, 256, 0, stream>>>(src, dst, etype, norm, offs, meta,
                                          nEdges, nBuck, chunk);
    sortB_kernel<<<nBuck, 256, 0, stream>>>(meta, bucketBase, endOff, nNodes);

    // ---- fused layers: 16 dsts/block (4 per wave), block-shared A-tile ----
    const int fBlocks = (nNodes + 15) / 16;             // 12500
    fused_kernel<64, ushort><<<fBlocks, 256, 0, stream>>>(
        embb, Wf1, meta, endOff, bias1, h1b, nNodes);
    fused_kernel<32, float><<<fBlocks, 256, 0, stream>>>(
        h1b, Wf2, meta, endOff, bias2, out, nNodes);
}